// Round 2
// baseline (2178.922 us; speedup 1.0000x reference)
//
#include <hip/hip_runtime.h>

#define NN 100000
#define NE 3200000
#define NB 1563            // ceil(NN/64) buckets of 64 receiver nodes
#define NG 8               // XCD groups (blockIdx & 7)
#define NB8 (NB * NG)      // 12504 sub-buckets
#define NBLK ((NN + 255) / 256)
#define HIST_GRID 1024     // must be identical for k_bhist and k_scatter

// ---------------- bucket histogram (per XCD group) ----------------

__global__ __launch_bounds__(256) void k_bhist(const int* __restrict__ recv, int* __restrict__ cnt) {
  __shared__ int h[NB];
  for (int i = threadIdx.x; i < NB; i += 256) h[i] = 0;
  __syncthreads();
  int g = blockIdx.x & 7;
  int stride = gridDim.x * 256;
  for (int i = blockIdx.x * 256 + threadIdx.x; i < NE; i += stride)
    atomicAdd(&h[recv[i] >> 6], 1);
  __syncthreads();
  for (int i = threadIdx.x; i < NB; i += 256) {
    int c = h[i];
    if (c) atomicAdd(&cnt[i * NG + g], c);
  }
}

// ---------------- exclusive scan of 12504 sub-bucket counts ----------------

__global__ __launch_bounds__(256) void k_bscan(const int* __restrict__ cnt, int* __restrict__ boff,
                                               int* __restrict__ cursor) {
  __shared__ int ps[256];
  int t = threadIdx.x;
  const int PER = (NB8 + 255) / 256;  // 49
  int s = 0;
  for (int k = 0; k < PER; k++) {
    int i = t * PER + k;
    if (i < NB8) s += cnt[i];
  }
  ps[t] = s;
  __syncthreads();
  for (int o = 1; o < 256; o <<= 1) {
    int x = (t >= o) ? ps[t - o] : 0;
    __syncthreads();
    ps[t] += x;
    __syncthreads();
  }
  int run = (t > 0) ? ps[t - 1] : 0;
  for (int k = 0; k < PER; k++) {
    int i = t * PER + k;
    if (i < NB8) {
      int c = cnt[i];
      boff[i] = run;
      cursor[i] = run;
      run += c;
    }
  }
  if (t == 255) boff[NB8] = ps[255];
}

// ---------------- scatter edges into bucket-major, XCD-sub-bucketed records ----------------

__global__ __launch_bounds__(256) void k_scatter(const int* __restrict__ send, const int* __restrict__ recv,
                                                 const float2* __restrict__ ef, const float* __restrict__ mask,
                                                 int* __restrict__ cursor, float4* __restrict__ sorted) {
  int g = blockIdx.x & 7;
  int stride = gridDim.x * 256;
  for (int i = blockIdx.x * 256 + threadIdx.x; i < NE; i += stride) {
    int r = recv[i];
    int pos = atomicAdd(&cursor[(r >> 6) * NG + g], 1);
    float2 e2 = ef[i];
    float4 v;
    v.x = __int_as_float((send[i] << 6) | (r & 63));  // 17b sender | 6b local receiver
    v.y = e2.x;
    v.z = e2.y;
    v.w = mask[i];
    sorted[pos] = v;
  }
}

// ---------------- init: h = PQ@W_in + b_in ; Vp=(1,0); layer-0 a,b projections ----------------

__global__ __launch_bounds__(256) void k_init(const float2* __restrict__ PQ,
                                              const float* __restrict__ Win, const float* __restrict__ bin,
                                              const float* __restrict__ Wm, const float* __restrict__ bm,
                                              float* __restrict__ h, float* __restrict__ a,
                                              float* __restrict__ bp, float2* __restrict__ Vp) {
  int n = blockIdx.x * 256 + threadIdx.x;
  if (n >= NN) return;
  float2 pq = PQ[n];
  float hh[32];
#pragma unroll
  for (int j = 0; j < 32; j++) hh[j] = fmaf(pq.x, Win[j], fmaf(pq.y, Win[32 + j], bin[j]));
  float4* h4 = (float4*)(h + n * 32);
#pragma unroll
  for (int j = 0; j < 8; j++) h4[j] = make_float4(hh[4*j], hh[4*j+1], hh[4*j+2], hh[4*j+3]);
  Vp[n] = make_float2(1.0f, 0.0f);
  // a = Wm[0]*1 + sum_k h[k]*Wm[2+k] ; b = Wm[34]*1 + sum_k h[k]*Wm[36+k] + bm
  float av[32], bv[32];
#pragma unroll
  for (int j = 0; j < 32; j++) { av[j] = Wm[j]; bv[j] = Wm[34 * 32 + j] + bm[j]; }
#pragma unroll 1
  for (int k = 0; k < 32; k++) {
    float hk = hh[k];
#pragma unroll
    for (int j = 0; j < 32; j++) {
      av[j] = fmaf(hk, Wm[(2 + k) * 32 + j], av[j]);
      bv[j] = fmaf(hk, Wm[(36 + k) * 32 + j], bv[j]);
    }
  }
  float4* a4 = (float4*)(a + n * 32);
  float4* b4 = (float4*)(bp + n * 32);
#pragma unroll
  for (int j = 0; j < 8; j++) {
    a4[j] = make_float4(av[4*j], av[4*j+1], av[4*j+2], av[4*j+3]);
    b4[j] = make_float4(bv[4*j], bv[4*j+1], bv[4*j+2], bv[4*j+3]);
  }
}

// ---------------- per-layer edge aggregation: one block per bucket, LDS atomics ----------------
// LDS layout swizzle: value (rl, c) lives at dword rl*32 + ((c + 4*rl) & 31)

__global__ __launch_bounds__(256) void k_agg(const float* __restrict__ a, const float* __restrict__ bp,
                                             const int* __restrict__ boff, const float4* __restrict__ sorted,
                                             const float* __restrict__ Wm, float* __restrict__ agg) {
  __shared__ float aggL[64 * 32];
  __shared__ float bpl[64 * 32];
  int t = threadIdx.x;
  int b = blockIdx.x;
  int n0 = b * 64;
  for (int i = t; i < 2048; i += 256) aggL[i] = 0.0f;
  for (int i = t; i < 2048; i += 256) {
    int rl = i >> 5, c = i & 31;
    int n = n0 + rl;
    float v = (n < NN) ? bp[n * 32 + c] : 0.0f;
    bpl[rl * 32 + ((c + 4 * rl) & 31)] = v;
  }
  int j = t & 7;  // channel group: channels 4j..4j+3
  float4 we0 = *(const float4*)(Wm + 68 * 32 + 4 * j);
  float4 we1 = *(const float4*)(Wm + 69 * 32 + 4 * j);
  __syncthreads();
  int e0 = boff[b * NG], e1 = boff[(b + 1) * NG];
  for (int e = e0 + (t >> 3); e < e1; e += 32) {
    float4 ed = sorted[e];
    int pk = __float_as_int(ed.x);
    int s = pk >> 6, rl = pk & 63;
    float c0 = ed.y, c1 = ed.z, mk = ed.w;
    const float4 av = *(const float4*)(a + s * 32 + 4 * j);
    int li = rl * 32 + ((4 * j + 4 * rl) & 31);
    float4 bn = *(float4*)&bpl[li];
    float m0 = fmaxf(av.x + fmaf(c0, we0.x, fmaf(c1, we1.x, bn.x)), 0.0f) * mk;
    float m1 = fmaxf(av.y + fmaf(c0, we0.y, fmaf(c1, we1.y, bn.y)), 0.0f) * mk;
    float m2 = fmaxf(av.z + fmaf(c0, we0.z, fmaf(c1, we1.z, bn.z)), 0.0f) * mk;
    float m3 = fmaxf(av.w + fmaf(c0, we0.w, fmaf(c1, we1.w, bn.w)), 0.0f) * mk;
    atomicAdd(&aggL[li + 0], m0);
    atomicAdd(&aggL[li + 1], m1);
    atomicAdd(&aggL[li + 2], m2);
    atomicAdd(&aggL[li + 3], m3);
  }
  __syncthreads();
  for (int i = t; i < 2048; i += 256) {
    int rl = i >> 5, c = i & 31;
    int n = n0 + rl;
    if (n < NN) agg[n * 32 + c] = aggL[rl * 32 + ((c + 4 * rl) & 31)];
  }
}

// ---------------- per-layer node update (+ next-layer projections fused) ----------------

__global__ __launch_bounds__(256) void k_node(const float* __restrict__ agg,
                                              const float* __restrict__ Wu, const float* __restrict__ bu,
                                              const float* __restrict__ Wd, const float* __restrict__ bd,
                                              const float* __restrict__ Wm, const float* __restrict__ bm,
                                              float* __restrict__ h, float* __restrict__ a,
                                              float* __restrict__ bp, float2* __restrict__ Vp,
                                              float2* __restrict__ out, int last) {
  int n = blockIdx.x * 256 + threadIdx.x;
  if (n >= NN) return;
  float2 vp = Vp[n];
  float v0 = vp.x, v1 = vp.y;
  float hh[32], ag[32];
  const float4* h4 = (const float4*)(h + n * 32);
  const float4* g4 = (const float4*)(agg + n * 32);
#pragma unroll
  for (int jj = 0; jj < 8; jj++) {
    float4 x = h4[jj];
    hh[4*jj] = x.x; hh[4*jj+1] = x.y; hh[4*jj+2] = x.z; hh[4*jj+3] = x.w;
    float4 y = g4[jj];
    ag[4*jj] = y.x; ag[4*jj+1] = y.y; ag[4*jj+2] = y.z; ag[4*jj+3] = y.w;
  }
  // v_out = [Vp, h, agg] @ W_upd + b_upd
  float vo[32];
#pragma unroll
  for (int j = 0; j < 32; j++) vo[j] = fmaf(v0, Wu[j], fmaf(v1, Wu[32 + j], bu[j]));
#pragma unroll 1
  for (int k = 0; k < 32; k++) {
    float hk = hh[k], ak = ag[k];
#pragma unroll
    for (int j = 0; j < 32; j++) {
      vo[j] = fmaf(hk, Wu[(2 + k) * 32 + j], vo[j]);
      vo[j] = fmaf(ak, Wu[(34 + k) * 32 + j], vo[j]);
    }
  }
#pragma unroll
  for (int j = 0; j < 32; j++) hh[j] = fmaxf(vo[j], 0.0f);
  // delta_V
  float d0 = bd[0], d1 = bd[1];
#pragma unroll 1
  for (int k = 0; k < 32; k++) {
    d0 = fmaf(hh[k], Wd[2 * k], d0);
    d1 = fmaf(hh[k], Wd[2 * k + 1], d1);
  }
  v0 += d0;
  v1 += d1;
  if (last) {
    out[n] = make_float2(v0, v1);
    return;
  }
  Vp[n] = make_float2(v0, v1);
  float4* hw4 = (float4*)(h + n * 32);
#pragma unroll
  for (int jj = 0; jj < 8; jj++) hw4[jj] = make_float4(hh[4*jj], hh[4*jj+1], hh[4*jj+2], hh[4*jj+3]);
  // next-layer a,b projections
  float av[32], bv[32];
#pragma unroll
  for (int j = 0; j < 32; j++) {
    av[j] = fmaf(v0, Wm[j], v1 * Wm[32 + j]);
    bv[j] = fmaf(v0, Wm[34 * 32 + j], fmaf(v1, Wm[35 * 32 + j], bm[j]));
  }
#pragma unroll 1
  for (int k = 0; k < 32; k++) {
    float hk = hh[k];
#pragma unroll
    for (int j = 0; j < 32; j++) {
      av[j] = fmaf(hk, Wm[(2 + k) * 32 + j], av[j]);
      bv[j] = fmaf(hk, Wm[(36 + k) * 32 + j], bv[j]);
    }
  }
  float4* a4 = (float4*)(a + n * 32);
  float4* b4 = (float4*)(bp + n * 32);
#pragma unroll
  for (int jj = 0; jj < 8; jj++) {
    a4[jj] = make_float4(av[4*jj], av[4*jj+1], av[4*jj+2], av[4*jj+3]);
    b4[jj] = make_float4(bv[4*jj], bv[4*jj+1], bv[4*jj+2], bv[4*jj+3]);
  }
}

// ---------------- launch ----------------

extern "C" void kernel_launch(void* const* d_in, const int* in_sizes, int n_in,
                              void* d_out, int out_size, void* d_ws, size_t ws_size,
                              hipStream_t stream) {
  const float* PQ   = (const float*)d_in[0];
  const int*   send = (const int*)d_in[1];
  const int*   recv = (const int*)d_in[2];
  const float* ef   = (const float*)d_in[3];
  const float* mask = (const float*)d_in[4];
  const float* Win  = (const float*)d_in[5];
  const float* bin  = (const float*)d_in[6];
  const float* Wmsg = (const float*)d_in[7];   // [3,70,32]
  const float* bmsg = (const float*)d_in[8];   // [3,32]
  const float* Wupd = (const float*)d_in[9];   // [3,66,32]
  const float* bupd = (const float*)d_in[10];  // [3,32]
  const float* Wdel = (const float*)d_in[11];  // [3,32,2]
  const float* bdel = (const float*)d_in[12];  // [3,2]
  float2* out = (float2*)d_out;

  char* w = (char*)d_ws;
  auto alloc = [&](size_t bytes) {
    char* p = w;
    w += (bytes + 255) & ~(size_t)255;
    return p;
  };
  float4* sorted = (float4*)alloc((size_t)NE * 16);
  int* cnt    = (int*)alloc((size_t)NB8 * 4);
  int* boff   = (int*)alloc(((size_t)NB8 + 1) * 4);
  int* cursor = (int*)alloc((size_t)NB8 * 4);
  float* h    = (float*)alloc((size_t)NN * 32 * 4);
  float* a    = (float*)alloc((size_t)NN * 32 * 4);
  float* bp   = (float*)alloc((size_t)NN * 32 * 4);
  float* agg  = (float*)alloc((size_t)NN * 32 * 4);
  float2* Vp  = (float2*)alloc((size_t)NN * 8);

  hipMemsetAsync(cnt, 0, (size_t)NB8 * 4, stream);
  k_bhist<<<HIST_GRID, 256, 0, stream>>>(recv, cnt);
  k_bscan<<<1, 256, 0, stream>>>(cnt, boff, cursor);
  k_scatter<<<HIST_GRID, 256, 0, stream>>>(send, recv, (const float2*)ef, mask, cursor, sorted);

  k_init<<<NBLK, 256, 0, stream>>>((const float2*)PQ, Win, bin, Wmsg, bmsg, h, a, bp, Vp);

  for (int l = 0; l < 3; l++) {
    int last = (l == 2) ? 1 : 0;
    int lnext = (l + 1) % 3;
    k_agg<<<NB, 256, 0, stream>>>(a, bp, boff, sorted, Wmsg + l * 70 * 32, agg);
    k_node<<<NBLK, 256, 0, stream>>>(agg, Wupd + l * 66 * 32, bupd + l * 32,
                                     Wdel + l * 64, bdel + l * 2,
                                     Wmsg + lnext * 70 * 32, bmsg + lnext * 32,
                                     h, a, bp, Vp, out, last);
  }
}

// Round 3
// 1315.258 us; speedup vs baseline: 1.6566x; 1.6566x over previous
//
#include <hip/hip_runtime.h>

#define NN 100000
#define NE 3200000
#define NB 1563            // ceil(NN/64) buckets of 64 receiver nodes
#define NG 8               // XCD groups (blockIdx & 7)
#define NB8 (NB * NG)      // 12504 sub-buckets
#define NBLK ((NN + 255) / 256)
#define EBX ((NN + 127) / 128)   // 782 node-blocks for k_edge
#define HIST_GRID 1024
#define CAP 4096           // max edges per 64-node bucket (mean 2048, sigma ~45)

// ---------------- bucket histogram (per XCD group) ----------------

__global__ __launch_bounds__(256) void k_bhist(const int* __restrict__ recv, int* __restrict__ cnt) {
  __shared__ int h[NB];
  for (int i = threadIdx.x; i < NB; i += 256) h[i] = 0;
  __syncthreads();
  int g = blockIdx.x & 7;
  int stride = gridDim.x * 256;
  for (int i = blockIdx.x * 256 + threadIdx.x; i < NE; i += stride)
    atomicAdd(&h[recv[i] >> 6], 1);
  __syncthreads();
  for (int i = threadIdx.x; i < NB; i += 256) {
    int c = h[i];
    if (c) atomicAdd(&cnt[i * NG + g], c);
  }
}

// ---------------- exclusive scan of 12504 sub-bucket counts ----------------

__global__ __launch_bounds__(256) void k_bscan(const int* __restrict__ cnt, int* __restrict__ boff,
                                               int* __restrict__ cursor) {
  __shared__ int ps[256];
  int t = threadIdx.x;
  const int PER = (NB8 + 255) / 256;  // 49
  int s = 0;
  for (int k = 0; k < PER; k++) {
    int i = t * PER + k;
    if (i < NB8) s += cnt[i];
  }
  ps[t] = s;
  __syncthreads();
  for (int o = 1; o < 256; o <<= 1) {
    int x = (t >= o) ? ps[t - o] : 0;
    __syncthreads();
    ps[t] += x;
    __syncthreads();
  }
  int run = (t > 0) ? ps[t - 1] : 0;
  for (int k = 0; k < PER; k++) {
    int i = t * PER + k;
    if (i < NB8) {
      int c = cnt[i];
      boff[i] = run;
      cursor[i] = run;
      run += c;
    }
  }
  if (t == 255) boff[NB8] = ps[255];
}

// ---------------- scatter edges into bucket-major, XCD-sub-bucketed records ----------------

__global__ __launch_bounds__(256) void k_scatter(const int* __restrict__ send, const int* __restrict__ recv,
                                                 const float2* __restrict__ ef, const float* __restrict__ mask,
                                                 int* __restrict__ cursor, float4* __restrict__ sorted) {
  int g = blockIdx.x & 7;
  int stride = gridDim.x * 256;
  for (int i = blockIdx.x * 256 + threadIdx.x; i < NE; i += stride) {
    int r = recv[i];
    int pos = atomicAdd(&cursor[(r >> 6) * NG + g], 1);
    float2 e2 = ef[i];
    float4 v;
    v.x = __int_as_float((send[i] << 6) | (r & 63));  // 17b sender | 6b local receiver
    v.y = e2.x;
    v.z = e2.y;
    v.w = mask[i];
    sorted[pos] = v;
  }
}

// ---------------- per-bucket in-place counting sort -> node-major + row_off ----------------

__global__ __launch_bounds__(256) void k_bsort(const int* __restrict__ boff, float4* __restrict__ sorted,
                                               int* __restrict__ row_off) {
  __shared__ int cnt[64];
  __shared__ int cur[64];
  __shared__ float4 stg[CAP];
  int t = threadIdx.x, b = blockIdx.x;
  int base = boff[b * NG], end = boff[(b + 1) * NG];
  int Eb = end - base;
  int n0 = b * 64;
  if (t < 64) cnt[t] = 0;
  __syncthreads();
  for (int e = base + t; e < end; e += 256)
    atomicAdd(&cnt[__float_as_int(sorted[e].x) & 63], 1);
  __syncthreads();
  int c = (t < 64) ? cnt[t] : 0;
  __syncthreads();
  for (int o = 1; o < 64; o <<= 1) {
    int x = (t < 64 && t >= o) ? cnt[t - o] : 0;
    __syncthreads();
    if (t < 64) cnt[t] += x;
    __syncthreads();
  }
  if (t < 64) {
    int exc = cnt[t] - c;
    cur[t] = exc;
    int n = n0 + t;
    if (n < NN) row_off[n] = base + exc;
  }
  if (b == NB - 1 && t == 0) row_off[NN] = end;
  __syncthreads();
  for (int e = base + t; e < end; e += 256) {
    float4 r = sorted[e];
    int rl = __float_as_int(r.x) & 63;
    int p = atomicAdd(&cur[rl], 1);
    stg[p] = r;
  }
  __syncthreads();
  for (int i = t; i < Eb; i += 256) sorted[base + i] = stg[i];
}

// ---------------- init: h = PQ@W_in + b_in ; Vp=(1,0); layer-0 a,b projections ----------------
// a,bp stored quarter-major: aq(q,n,j) = a[(q*NN + n)*8 + j], j in [0,8)

__global__ __launch_bounds__(256) void k_init(const float2* __restrict__ PQ,
                                              const float* __restrict__ Win, const float* __restrict__ bin,
                                              const float* __restrict__ Wm, const float* __restrict__ bm,
                                              float* __restrict__ h, float* __restrict__ a,
                                              float* __restrict__ bp, float2* __restrict__ Vp) {
  int n = blockIdx.x * 256 + threadIdx.x;
  if (n >= NN) return;
  float2 pq = PQ[n];
  float hh[32];
#pragma unroll
  for (int j = 0; j < 32; j++) hh[j] = fmaf(pq.x, Win[j], fmaf(pq.y, Win[32 + j], bin[j]));
  float4* h4 = (float4*)(h + (size_t)n * 32);
#pragma unroll
  for (int j = 0; j < 8; j++) h4[j] = make_float4(hh[4*j], hh[4*j+1], hh[4*j+2], hh[4*j+3]);
  Vp[n] = make_float2(1.0f, 0.0f);
  float av[32], bv[32];
#pragma unroll
  for (int j = 0; j < 32; j++) { av[j] = Wm[j]; bv[j] = Wm[34 * 32 + j] + bm[j]; }
#pragma unroll 1
  for (int k = 0; k < 32; k++) {
    float hk = hh[k];
#pragma unroll
    for (int j = 0; j < 32; j++) {
      av[j] = fmaf(hk, Wm[(2 + k) * 32 + j], av[j]);
      bv[j] = fmaf(hk, Wm[(36 + k) * 32 + j], bv[j]);
    }
  }
#pragma unroll
  for (int q = 0; q < 4; q++) {
    float* ap = a + ((size_t)q * NN + n) * 8;
    float* bpq = bp + ((size_t)q * NN + n) * 8;
    *(float4*)ap       = make_float4(av[q*8+0], av[q*8+1], av[q*8+2], av[q*8+3]);
    *(float4*)(ap + 4) = make_float4(av[q*8+4], av[q*8+5], av[q*8+6], av[q*8+7]);
    *(float4*)bpq       = make_float4(bv[q*8+0], bv[q*8+1], bv[q*8+2], bv[q*8+3]);
    *(float4*)(bpq + 4) = make_float4(bv[q*8+4], bv[q*8+5], bv[q*8+6], bv[q*8+7]);
  }
}

// ---------------- per-layer edge aggregation: per-node CSR gather, channel-quartered ----------------
// blockIdx&3 = channel quarter q (maps to XCDs {q,q+4}); each XCD's a-slice = 3.2MB, fits 4MB L2.

__global__ __launch_bounds__(128) void k_edge(const float* __restrict__ a, const float* __restrict__ bp,
                                              const int* __restrict__ row_off, const float4* __restrict__ sorted,
                                              const float* __restrict__ Wm, float* __restrict__ agg) {
  int q = blockIdx.x & 3;
  int n = (blockIdx.x >> 2) * 128 + threadIdx.x;
  if (n >= NN) return;
  const float* wr = Wm + 68 * 32 + q * 8;
  float4 w0a = *(const float4*)wr,        w0b = *(const float4*)(wr + 4);
  float4 w1a = *(const float4*)(wr + 32), w1b = *(const float4*)(wr + 36);
  const float* bq = bp + ((size_t)q * NN + n) * 8;
  float4 bna = *(const float4*)bq, bnb = *(const float4*)(bq + 4);
  float4 acc0 = make_float4(0.f, 0.f, 0.f, 0.f);
  float4 acc1 = make_float4(0.f, 0.f, 0.f, 0.f);
  int e0 = row_off[n], e1 = row_off[n + 1];
  float4 rec;
  if (e0 < e1) rec = sorted[e0];
  for (int e = e0; e < e1; ++e) {
    int pk = __float_as_int(rec.x);
    float c0 = rec.y, c1 = rec.z, mk = rec.w;
    if (e + 1 < e1) rec = sorted[e + 1];  // prefetch next record
    const float* ap = a + ((size_t)q * NN + (pk >> 6)) * 8;
    float4 g0 = *(const float4*)ap, g1 = *(const float4*)(ap + 4);
    acc0.x = fmaf(fmaxf(g0.x + fmaf(c0, w0a.x, fmaf(c1, w1a.x, bna.x)), 0.f), mk, acc0.x);
    acc0.y = fmaf(fmaxf(g0.y + fmaf(c0, w0a.y, fmaf(c1, w1a.y, bna.y)), 0.f), mk, acc0.y);
    acc0.z = fmaf(fmaxf(g0.z + fmaf(c0, w0a.z, fmaf(c1, w1a.z, bna.z)), 0.f), mk, acc0.z);
    acc0.w = fmaf(fmaxf(g0.w + fmaf(c0, w0a.w, fmaf(c1, w1a.w, bna.w)), 0.f), mk, acc0.w);
    acc1.x = fmaf(fmaxf(g1.x + fmaf(c0, w0b.x, fmaf(c1, w1b.x, bnb.x)), 0.f), mk, acc1.x);
    acc1.y = fmaf(fmaxf(g1.y + fmaf(c0, w0b.y, fmaf(c1, w1b.y, bnb.y)), 0.f), mk, acc1.y);
    acc1.z = fmaf(fmaxf(g1.z + fmaf(c0, w0b.z, fmaf(c1, w1b.z, bnb.z)), 0.f), mk, acc1.z);
    acc1.w = fmaf(fmaxf(g1.w + fmaf(c0, w0b.w, fmaf(c1, w1b.w, bnb.w)), 0.f), mk, acc1.w);
  }
  float* gp = agg + ((size_t)q * NN + n) * 8;
  *(float4*)gp       = acc0;
  *(float4*)(gp + 4) = acc1;
}

// ---------------- per-layer node update (+ next-layer projections fused) ----------------

__global__ __launch_bounds__(256) void k_node(const float* __restrict__ agg,
                                              const float* __restrict__ Wu, const float* __restrict__ bu,
                                              const float* __restrict__ Wd, const float* __restrict__ bd,
                                              const float* __restrict__ Wm, const float* __restrict__ bm,
                                              float* __restrict__ h, float* __restrict__ a,
                                              float* __restrict__ bp, float2* __restrict__ Vp,
                                              float2* __restrict__ out, int last) {
  int n = blockIdx.x * 256 + threadIdx.x;
  if (n >= NN) return;
  float2 vp = Vp[n];
  float v0 = vp.x, v1 = vp.y;
  float hh[32], ag[32];
  const float4* h4 = (const float4*)(h + (size_t)n * 32);
#pragma unroll
  for (int jj = 0; jj < 8; jj++) {
    float4 x = h4[jj];
    hh[4*jj] = x.x; hh[4*jj+1] = x.y; hh[4*jj+2] = x.z; hh[4*jj+3] = x.w;
  }
#pragma unroll
  for (int q = 0; q < 4; q++) {
    const float* gp = agg + ((size_t)q * NN + n) * 8;
    float4 y0 = *(const float4*)gp, y1 = *(const float4*)(gp + 4);
    ag[q*8+0] = y0.x; ag[q*8+1] = y0.y; ag[q*8+2] = y0.z; ag[q*8+3] = y0.w;
    ag[q*8+4] = y1.x; ag[q*8+5] = y1.y; ag[q*8+6] = y1.z; ag[q*8+7] = y1.w;
  }
  float vo[32];
#pragma unroll
  for (int j = 0; j < 32; j++) vo[j] = fmaf(v0, Wu[j], fmaf(v1, Wu[32 + j], bu[j]));
#pragma unroll 1
  for (int k = 0; k < 32; k++) {
    float hk = hh[k], ak = ag[k];
#pragma unroll
    for (int j = 0; j < 32; j++) {
      vo[j] = fmaf(hk, Wu[(2 + k) * 32 + j], vo[j]);
      vo[j] = fmaf(ak, Wu[(34 + k) * 32 + j], vo[j]);
    }
  }
#pragma unroll
  for (int j = 0; j < 32; j++) hh[j] = fmaxf(vo[j], 0.0f);
  float d0 = bd[0], d1 = bd[1];
#pragma unroll 1
  for (int k = 0; k < 32; k++) {
    d0 = fmaf(hh[k], Wd[2 * k], d0);
    d1 = fmaf(hh[k], Wd[2 * k + 1], d1);
  }
  v0 += d0;
  v1 += d1;
  if (last) {
    out[n] = make_float2(v0, v1);
    return;
  }
  Vp[n] = make_float2(v0, v1);
  float4* hw4 = (float4*)(h + (size_t)n * 32);
#pragma unroll
  for (int jj = 0; jj < 8; jj++) hw4[jj] = make_float4(hh[4*jj], hh[4*jj+1], hh[4*jj+2], hh[4*jj+3]);
  float av[32], bv[32];
#pragma unroll
  for (int j = 0; j < 32; j++) {
    av[j] = fmaf(v0, Wm[j], v1 * Wm[32 + j]);
    bv[j] = fmaf(v0, Wm[34 * 32 + j], fmaf(v1, Wm[35 * 32 + j], bm[j]));
  }
#pragma unroll 1
  for (int k = 0; k < 32; k++) {
    float hk = hh[k];
#pragma unroll
    for (int j = 0; j < 32; j++) {
      av[j] = fmaf(hk, Wm[(2 + k) * 32 + j], av[j]);
      bv[j] = fmaf(hk, Wm[(36 + k) * 32 + j], bv[j]);
    }
  }
#pragma unroll
  for (int q = 0; q < 4; q++) {
    float* ap = a + ((size_t)q * NN + n) * 8;
    float* bpq = bp + ((size_t)q * NN + n) * 8;
    *(float4*)ap       = make_float4(av[q*8+0], av[q*8+1], av[q*8+2], av[q*8+3]);
    *(float4*)(ap + 4) = make_float4(av[q*8+4], av[q*8+5], av[q*8+6], av[q*8+7]);
    *(float4*)bpq       = make_float4(bv[q*8+0], bv[q*8+1], bv[q*8+2], bv[q*8+3]);
    *(float4*)(bpq + 4) = make_float4(bv[q*8+4], bv[q*8+5], bv[q*8+6], bv[q*8+7]);
  }
}

// ---------------- launch ----------------

extern "C" void kernel_launch(void* const* d_in, const int* in_sizes, int n_in,
                              void* d_out, int out_size, void* d_ws, size_t ws_size,
                              hipStream_t stream) {
  const float* PQ   = (const float*)d_in[0];
  const int*   send = (const int*)d_in[1];
  const int*   recv = (const int*)d_in[2];
  const float* ef   = (const float*)d_in[3];
  const float* mask = (const float*)d_in[4];
  const float* Win  = (const float*)d_in[5];
  const float* bin  = (const float*)d_in[6];
  const float* Wmsg = (const float*)d_in[7];   // [3,70,32]
  const float* bmsg = (const float*)d_in[8];   // [3,32]
  const float* Wupd = (const float*)d_in[9];   // [3,66,32]
  const float* bupd = (const float*)d_in[10];  // [3,32]
  const float* Wdel = (const float*)d_in[11];  // [3,32,2]
  const float* bdel = (const float*)d_in[12];  // [3,2]
  float2* out = (float2*)d_out;

  char* w = (char*)d_ws;
  auto alloc = [&](size_t bytes) {
    char* p = w;
    w += (bytes + 255) & ~(size_t)255;
    return p;
  };
  float4* sorted = (float4*)alloc((size_t)NE * 16);
  int* cnt     = (int*)alloc((size_t)NB8 * 4);
  int* boff    = (int*)alloc(((size_t)NB8 + 1) * 4);
  int* cursor  = (int*)alloc((size_t)NB8 * 4);
  int* row_off = (int*)alloc(((size_t)NN + 1) * 4);
  float* h    = (float*)alloc((size_t)NN * 32 * 4);
  float* a    = (float*)alloc((size_t)NN * 32 * 4);
  float* bp   = (float*)alloc((size_t)NN * 32 * 4);
  float* agg  = (float*)alloc((size_t)NN * 32 * 4);
  float2* Vp  = (float2*)alloc((size_t)NN * 8);

  hipMemsetAsync(cnt, 0, (size_t)NB8 * 4, stream);
  k_bhist<<<HIST_GRID, 256, 0, stream>>>(recv, cnt);
  k_bscan<<<1, 256, 0, stream>>>(cnt, boff, cursor);
  k_scatter<<<HIST_GRID, 256, 0, stream>>>(send, recv, (const float2*)ef, mask, cursor, sorted);
  k_bsort<<<NB, 256, 0, stream>>>(boff, sorted, row_off);

  k_init<<<NBLK, 256, 0, stream>>>((const float2*)PQ, Win, bin, Wmsg, bmsg, h, a, bp, Vp);

  for (int l = 0; l < 3; l++) {
    int last = (l == 2) ? 1 : 0;
    int lnext = (l + 1) % 3;
    k_edge<<<EBX * 4, 128, 0, stream>>>(a, bp, row_off, sorted, Wmsg + l * 70 * 32, agg);
    k_node<<<NBLK, 256, 0, stream>>>(agg, Wupd + l * 66 * 32, bupd + l * 32,
                                     Wdel + l * 64, bdel + l * 2,
                                     Wmsg + lnext * 70 * 32, bmsg + lnext * 32,
                                     h, a, bp, Vp, out, last);
  }
}

// Round 4
// 900.556 us; speedup vs baseline: 2.4195x; 1.4605x over previous
//
#include <hip/hip_runtime.h>
#include <hip/hip_fp16.h>

#define NN 100000
#define NE 3200000
#define NB 1563            // ceil(NN/64) buckets of 64 receiver nodes
#define NG 8               // XCD groups (blockIdx & 7)
#define NB8 (NB * NG)      // 12504 sub-buckets
#define NBLK ((NN + 255) / 256)
#define EB2 ((NN + 127) / 128)   // node-blocks for k_edge (128 nodes/block)
#define HIST_GRID 1024
#define CAP 4096           // max edges per 64-node bucket (mean 2048, sigma ~45)

typedef float f32x4 __attribute__((ext_vector_type(4)));
typedef unsigned int u32x4 __attribute__((ext_vector_type(4)));

__device__ __forceinline__ float2 h2f2(unsigned int u) {
  __half2 h;
  *reinterpret_cast<unsigned int*>(&h) = u;
  return __half22float2(h);
}
__device__ __forceinline__ unsigned int f2h2(float x, float y) {
  __half2 h = __floats2half2_rn(x, y);
  return *reinterpret_cast<unsigned int*>(&h);
}

// ---------------- bucket histogram (per XCD group) ----------------

__global__ __launch_bounds__(256) void k_bhist(const int* __restrict__ recv, int* __restrict__ cnt) {
  __shared__ int h[NB];
  for (int i = threadIdx.x; i < NB; i += 256) h[i] = 0;
  __syncthreads();
  int g = blockIdx.x & 7;
  int stride = gridDim.x * 256;
  for (int i = blockIdx.x * 256 + threadIdx.x; i < NE; i += stride)
    atomicAdd(&h[recv[i] >> 6], 1);
  __syncthreads();
  for (int i = threadIdx.x; i < NB; i += 256) {
    int c = h[i];
    if (c) atomicAdd(&cnt[i * NG + g], c);
  }
}

// ---------------- exclusive scan of 12504 sub-bucket counts ----------------

__global__ __launch_bounds__(256) void k_bscan(const int* __restrict__ cnt, int* __restrict__ boff,
                                               int* __restrict__ cursor) {
  __shared__ int ps[256];
  int t = threadIdx.x;
  const int PER = (NB8 + 255) / 256;  // 49
  int s = 0;
  for (int k = 0; k < PER; k++) {
    int i = t * PER + k;
    if (i < NB8) s += cnt[i];
  }
  ps[t] = s;
  __syncthreads();
  for (int o = 1; o < 256; o <<= 1) {
    int x = (t >= o) ? ps[t - o] : 0;
    __syncthreads();
    ps[t] += x;
    __syncthreads();
  }
  int run = (t > 0) ? ps[t - 1] : 0;
  for (int k = 0; k < PER; k++) {
    int i = t * PER + k;
    if (i < NB8) {
      int c = cnt[i];
      boff[i] = run;
      cursor[i] = run;
      run += c;
    }
  }
  if (t == 255) boff[NB8] = ps[255];
}

// ---------------- scatter edges into bucket-major, XCD-sub-bucketed records ----------------

__global__ __launch_bounds__(256) void k_scatter(const int* __restrict__ send, const int* __restrict__ recv,
                                                 const float2* __restrict__ ef, const float* __restrict__ mask,
                                                 int* __restrict__ cursor, float4* __restrict__ sorted) {
  int g = blockIdx.x & 7;
  int stride = gridDim.x * 256;
  for (int i = blockIdx.x * 256 + threadIdx.x; i < NE; i += stride) {
    int r = recv[i];
    int pos = atomicAdd(&cursor[(r >> 6) * NG + g], 1);
    float2 e2 = ef[i];
    float4 v;
    v.x = __int_as_float((send[i] << 6) | (r & 63));  // 17b sender | 6b local receiver
    v.y = e2.x;
    v.z = e2.y;
    v.w = mask[i];
    sorted[pos] = v;
  }
}

// ---------------- per-bucket in-place counting sort -> node-major + row_off ----------------

__global__ __launch_bounds__(256) void k_bsort(const int* __restrict__ boff, float4* __restrict__ sorted,
                                               int* __restrict__ row_off) {
  __shared__ int cnt[64];
  __shared__ int cur[64];
  __shared__ float4 stg[CAP];
  int t = threadIdx.x, b = blockIdx.x;
  int base = boff[b * NG], end = boff[(b + 1) * NG];
  int Eb = end - base;
  int n0 = b * 64;
  if (t < 64) cnt[t] = 0;
  __syncthreads();
  for (int e = base + t; e < end; e += 256)
    atomicAdd(&cnt[__float_as_int(sorted[e].x) & 63], 1);
  __syncthreads();
  int c = (t < 64) ? cnt[t] : 0;
  __syncthreads();
  for (int o = 1; o < 64; o <<= 1) {
    int x = (t < 64 && t >= o) ? cnt[t - o] : 0;
    __syncthreads();
    if (t < 64) cnt[t] += x;
    __syncthreads();
  }
  if (t < 64) {
    int exc = cnt[t] - c;
    cur[t] = exc;
    int n = n0 + t;
    if (n < NN) row_off[n] = base + exc;
  }
  if (b == NB - 1 && t == 0) row_off[NN] = end;
  __syncthreads();
  for (int e = base + t; e < end; e += 256) {
    float4 r = sorted[e];
    int rl = __float_as_int(r.x) & 63;
    int p = atomicAdd(&cur[rl], 1);
    stg[p] = r;
  }
  __syncthreads();
  for (int i = t; i < Eb; i += 256) sorted[base + i] = stg[i];
}

// ---------------- init: h = PQ@W_in + b_in ; Vp=(1,0); layer-0 a,b projections ----------------
// a stored fp16, group-major: a[((g*NN + n)*16 + j] for channel g*16+j, g in {0,1}

__global__ __launch_bounds__(256) void k_init(const float2* __restrict__ PQ,
                                              const float* __restrict__ Win, const float* __restrict__ bin,
                                              const float* __restrict__ Wm, const float* __restrict__ bm,
                                              float* __restrict__ h, __half* __restrict__ a,
                                              float* __restrict__ bp, float2* __restrict__ Vp) {
  int n = blockIdx.x * 256 + threadIdx.x;
  if (n >= NN) return;
  float2 pq = PQ[n];
  float hh[32];
#pragma unroll
  for (int j = 0; j < 32; j++) hh[j] = fmaf(pq.x, Win[j], fmaf(pq.y, Win[32 + j], bin[j]));
  float4* h4 = (float4*)(h + (size_t)n * 32);
#pragma unroll
  for (int j = 0; j < 8; j++) h4[j] = make_float4(hh[4*j], hh[4*j+1], hh[4*j+2], hh[4*j+3]);
  Vp[n] = make_float2(1.0f, 0.0f);
  float av[32], bv[32];
#pragma unroll
  for (int j = 0; j < 32; j++) { av[j] = Wm[j]; bv[j] = Wm[34 * 32 + j] + bm[j]; }
#pragma unroll 1
  for (int k = 0; k < 32; k++) {
    float hk = hh[k];
#pragma unroll
    for (int j = 0; j < 32; j++) {
      av[j] = fmaf(hk, Wm[(2 + k) * 32 + j], av[j]);
      bv[j] = fmaf(hk, Wm[(36 + k) * 32 + j], bv[j]);
    }
  }
#pragma unroll
  for (int g = 0; g < 2; g++) {
    u32x4 p0, p1;
    p0.x = f2h2(av[g*16+0],  av[g*16+1]);  p0.y = f2h2(av[g*16+2],  av[g*16+3]);
    p0.z = f2h2(av[g*16+4],  av[g*16+5]);  p0.w = f2h2(av[g*16+6],  av[g*16+7]);
    p1.x = f2h2(av[g*16+8],  av[g*16+9]);  p1.y = f2h2(av[g*16+10], av[g*16+11]);
    p1.z = f2h2(av[g*16+12], av[g*16+13]); p1.w = f2h2(av[g*16+14], av[g*16+15]);
    u32x4* dst = (u32x4*)(a + ((size_t)g * NN + n) * 16);
    dst[0] = p0;
    dst[1] = p1;
  }
  float4* b4 = (float4*)(bp + (size_t)n * 32);
#pragma unroll
  for (int j = 0; j < 8; j++) b4[j] = make_float4(bv[4*j], bv[4*j+1], bv[4*j+2], bv[4*j+3]);
}

// ---------------- per-layer edge aggregation: lane-paired CSR gather, fp16 a, nt stream ----------------
// blockIdx&1 = channel group g (16 ch); slice a[g] = 3.2MB per XCD -> L2-resident.
// Lane pair (t>>1 = node, t&1 = 8-ch half): record load is broadcast, gather is 32B coalesced.

__global__ __launch_bounds__(256) void k_edge(const __half* __restrict__ a, const float* __restrict__ bp,
                                              const int* __restrict__ row_off, const f32x4* __restrict__ sorted,
                                              const float* __restrict__ Wm, float* __restrict__ agg) {
  int t = threadIdx.x;
  int g = blockIdx.x & 1;
  int n = (blockIdx.x >> 1) * 128 + (t >> 1);
  if (n >= NN) return;
  int ch = g * 16 + (t & 1) * 8;
  const float* wr = Wm + 68 * 32 + ch;
  const float4 w0a = *(const float4*)wr,        w0b = *(const float4*)(wr + 4);
  const float4 w1a = *(const float4*)(wr + 32), w1b = *(const float4*)(wr + 36);
  const float4 bna = *(const float4*)(bp + (size_t)n * 32 + ch);
  const float4 bnb = *(const float4*)(bp + (size_t)n * 32 + ch + 4);
  float4 acc0 = make_float4(0.f, 0.f, 0.f, 0.f);
  float4 acc1 = make_float4(0.f, 0.f, 0.f, 0.f);
  int e0 = row_off[n], e1 = row_off[n + 1];
  const __half* abase = a + (size_t)g * NN * 16 + (t & 1) * 8;
  f32x4 rec = {0.f, 0.f, 0.f, 0.f};
  if (e0 < e1) rec = __builtin_nontemporal_load(sorted + e0);
  for (int e = e0; e < e1; ++e) {
    int pk = __float_as_int(rec.x);
    float c0 = rec.y, c1 = rec.z, mk = rec.w;
    if (e + 1 < e1) rec = __builtin_nontemporal_load(sorted + e + 1);  // nt prefetch next record
    const u32x4 pa = *(const u32x4*)(abase + (size_t)(pk >> 6) * 16);
    float2 f0 = h2f2(pa.x), f1 = h2f2(pa.y), f2 = h2f2(pa.z), f3 = h2f2(pa.w);
    acc0.x = fmaf(fmaxf(f0.x + fmaf(c0, w0a.x, fmaf(c1, w1a.x, bna.x)), 0.f), mk, acc0.x);
    acc0.y = fmaf(fmaxf(f0.y + fmaf(c0, w0a.y, fmaf(c1, w1a.y, bna.y)), 0.f), mk, acc0.y);
    acc0.z = fmaf(fmaxf(f1.x + fmaf(c0, w0a.z, fmaf(c1, w1a.z, bna.z)), 0.f), mk, acc0.z);
    acc0.w = fmaf(fmaxf(f1.y + fmaf(c0, w0a.w, fmaf(c1, w1a.w, bna.w)), 0.f), mk, acc0.w);
    acc1.x = fmaf(fmaxf(f2.x + fmaf(c0, w0b.x, fmaf(c1, w1b.x, bnb.x)), 0.f), mk, acc1.x);
    acc1.y = fmaf(fmaxf(f2.y + fmaf(c0, w0b.y, fmaf(c1, w1b.y, bnb.y)), 0.f), mk, acc1.y);
    acc1.z = fmaf(fmaxf(f3.x + fmaf(c0, w0b.z, fmaf(c1, w1b.z, bnb.z)), 0.f), mk, acc1.z);
    acc1.w = fmaf(fmaxf(f3.y + fmaf(c0, w0b.w, fmaf(c1, w1b.w, bnb.w)), 0.f), mk, acc1.w);
  }
  float* gp = agg + (size_t)n * 32 + ch;
  *(float4*)gp       = acc0;
  *(float4*)(gp + 4) = acc1;
}

// ---------------- per-layer node update (+ next-layer projections fused) ----------------

__global__ __launch_bounds__(256) void k_node(const float* __restrict__ agg,
                                              const float* __restrict__ Wu, const float* __restrict__ bu,
                                              const float* __restrict__ Wd, const float* __restrict__ bd,
                                              const float* __restrict__ Wm, const float* __restrict__ bm,
                                              float* __restrict__ h, __half* __restrict__ a,
                                              float* __restrict__ bp, float2* __restrict__ Vp,
                                              float2* __restrict__ out, int last) {
  int n = blockIdx.x * 256 + threadIdx.x;
  if (n >= NN) return;
  float2 vp = Vp[n];
  float v0 = vp.x, v1 = vp.y;
  float hh[32], ag[32];
  const float4* h4 = (const float4*)(h + (size_t)n * 32);
  const float4* g4 = (const float4*)(agg + (size_t)n * 32);
#pragma unroll
  for (int jj = 0; jj < 8; jj++) {
    float4 x = h4[jj];
    hh[4*jj] = x.x; hh[4*jj+1] = x.y; hh[4*jj+2] = x.z; hh[4*jj+3] = x.w;
    float4 y = g4[jj];
    ag[4*jj] = y.x; ag[4*jj+1] = y.y; ag[4*jj+2] = y.z; ag[4*jj+3] = y.w;
  }
  float vo[32];
#pragma unroll
  for (int j = 0; j < 32; j++) vo[j] = fmaf(v0, Wu[j], fmaf(v1, Wu[32 + j], bu[j]));
#pragma unroll 1
  for (int k = 0; k < 32; k++) {
    float hk = hh[k], ak = ag[k];
#pragma unroll
    for (int j = 0; j < 32; j++) {
      vo[j] = fmaf(hk, Wu[(2 + k) * 32 + j], vo[j]);
      vo[j] = fmaf(ak, Wu[(34 + k) * 32 + j], vo[j]);
    }
  }
#pragma unroll
  for (int j = 0; j < 32; j++) hh[j] = fmaxf(vo[j], 0.0f);
  float d0 = bd[0], d1 = bd[1];
#pragma unroll 1
  for (int k = 0; k < 32; k++) {
    d0 = fmaf(hh[k], Wd[2 * k], d0);
    d1 = fmaf(hh[k], Wd[2 * k + 1], d1);
  }
  v0 += d0;
  v1 += d1;
  if (last) {
    out[n] = make_float2(v0, v1);
    return;
  }
  Vp[n] = make_float2(v0, v1);
  float4* hw4 = (float4*)(h + (size_t)n * 32);
#pragma unroll
  for (int jj = 0; jj < 8; jj++) hw4[jj] = make_float4(hh[4*jj], hh[4*jj+1], hh[4*jj+2], hh[4*jj+3]);
  float av[32], bv[32];
#pragma unroll
  for (int j = 0; j < 32; j++) {
    av[j] = fmaf(v0, Wm[j], v1 * Wm[32 + j]);
    bv[j] = fmaf(v0, Wm[34 * 32 + j], fmaf(v1, Wm[35 * 32 + j], bm[j]));
  }
#pragma unroll 1
  for (int k = 0; k < 32; k++) {
    float hk = hh[k];
#pragma unroll
    for (int j = 0; j < 32; j++) {
      av[j] = fmaf(hk, Wm[(2 + k) * 32 + j], av[j]);
      bv[j] = fmaf(hk, Wm[(36 + k) * 32 + j], bv[j]);
    }
  }
#pragma unroll
  for (int g = 0; g < 2; g++) {
    u32x4 p0, p1;
    p0.x = f2h2(av[g*16+0],  av[g*16+1]);  p0.y = f2h2(av[g*16+2],  av[g*16+3]);
    p0.z = f2h2(av[g*16+4],  av[g*16+5]);  p0.w = f2h2(av[g*16+6],  av[g*16+7]);
    p1.x = f2h2(av[g*16+8],  av[g*16+9]);  p1.y = f2h2(av[g*16+10], av[g*16+11]);
    p1.z = f2h2(av[g*16+12], av[g*16+13]); p1.w = f2h2(av[g*16+14], av[g*16+15]);
    u32x4* dst = (u32x4*)(a + ((size_t)g * NN + n) * 16);
    dst[0] = p0;
    dst[1] = p1;
  }
  float4* b4 = (float4*)(bp + (size_t)n * 32);
#pragma unroll
  for (int jj = 0; jj < 8; jj++) b4[jj] = make_float4(bv[4*jj], bv[4*jj+1], bv[4*jj+2], bv[4*jj+3]);
}

// ---------------- launch ----------------

extern "C" void kernel_launch(void* const* d_in, const int* in_sizes, int n_in,
                              void* d_out, int out_size, void* d_ws, size_t ws_size,
                              hipStream_t stream) {
  const float* PQ   = (const float*)d_in[0];
  const int*   send = (const int*)d_in[1];
  const int*   recv = (const int*)d_in[2];
  const float* ef   = (const float*)d_in[3];
  const float* mask = (const float*)d_in[4];
  const float* Win  = (const float*)d_in[5];
  const float* bin  = (const float*)d_in[6];
  const float* Wmsg = (const float*)d_in[7];   // [3,70,32]
  const float* bmsg = (const float*)d_in[8];   // [3,32]
  const float* Wupd = (const float*)d_in[9];   // [3,66,32]
  const float* bupd = (const float*)d_in[10];  // [3,32]
  const float* Wdel = (const float*)d_in[11];  // [3,32,2]
  const float* bdel = (const float*)d_in[12];  // [3,2]
  float2* out = (float2*)d_out;

  char* w = (char*)d_ws;
  auto alloc = [&](size_t bytes) {
    char* p = w;
    w += (bytes + 255) & ~(size_t)255;
    return p;
  };
  float4* sorted = (float4*)alloc((size_t)NE * 16);
  int* cnt     = (int*)alloc((size_t)NB8 * 4);
  int* boff    = (int*)alloc(((size_t)NB8 + 1) * 4);
  int* cursor  = (int*)alloc((size_t)NB8 * 4);
  int* row_off = (int*)alloc(((size_t)NN + 1) * 4);
  float* h    = (float*)alloc((size_t)NN * 32 * 4);
  __half* a   = (__half*)alloc((size_t)NN * 32 * 2);
  float* bp   = (float*)alloc((size_t)NN * 32 * 4);
  float* agg  = (float*)alloc((size_t)NN * 32 * 4);
  float2* Vp  = (float2*)alloc((size_t)NN * 8);

  hipMemsetAsync(cnt, 0, (size_t)NB8 * 4, stream);
  k_bhist<<<HIST_GRID, 256, 0, stream>>>(recv, cnt);
  k_bscan<<<1, 256, 0, stream>>>(cnt, boff, cursor);
  k_scatter<<<HIST_GRID, 256, 0, stream>>>(send, recv, (const float2*)ef, mask, cursor, sorted);
  k_bsort<<<NB, 256, 0, stream>>>(boff, sorted, row_off);

  k_init<<<NBLK, 256, 0, stream>>>((const float2*)PQ, Win, bin, Wmsg, bmsg, h, a, bp, Vp);

  for (int l = 0; l < 3; l++) {
    int last = (l == 2) ? 1 : 0;
    int lnext = (l + 1) % 3;
    k_edge<<<EB2 * 2, 256, 0, stream>>>(a, bp, row_off, (const f32x4*)sorted,
                                        Wmsg + l * 70 * 32, agg);
    k_node<<<NBLK, 256, 0, stream>>>(agg, Wupd + l * 66 * 32, bupd + l * 32,
                                     Wdel + l * 64, bdel + l * 2,
                                     Wmsg + lnext * 70 * 32, bmsg + lnext * 32,
                                     h, a, bp, Vp, out, last);
  }
}